// Round 10
// baseline (98.278 us; speedup 1.0000x reference)
//
#include <hip/hip_runtime.h>

#define NQ 12
#define NLAYERS 8
#define BATCH 1024

typedef float v2f __attribute__((ext_vector_type(2)));

// ---------------------------------------------------------------------------
// CNOT folding (verified R2..R7): phys[p] = psi[L p], L = P^l.
//   RX(w) partner mask:  M_w(l) = { w+j : C(l,j) odd }
//   RZ(w) sign row:      R_w(l) = { w-j : C(l+j-1,j) odd }
// Placement (2 waves/state): p = (wv<<11)|(lane<<5)|j
//   wire0 = wv, wires1..6 = lane bits 5..0, wires7..11 = j bits 4..0.
// SoA packing: j = 2t+k ; re2[t]/im2[t] hold re/im of amps (2t,2t+1).
// R10: lane-crossing via __builtin_amdgcn_permlane32/16_swap (compiler-modeled;
//   R9's raw-asm version failed numerically) composed with DPP for low bits.
//   DS pipe carries ONLY one b128 full-state exchange per layer (wire0), and
//   each layer runs w1..w11 (pure VALU, exactly-commuting gates) first so the
//   two barriers are padded by VALU work.
// ---------------------------------------------------------------------------

constexpr bool codd(int n,int k){ return k==0 || (n>=0 && (k & ~n)==0); }
constexpr int Mwire(int l,int w){ int m=0; for(int j=0; w+j<=11; ++j) if(codd(l,j)) m|=1<<(w+j); return m; }
constexpr int Rwire(int l,int w){ int m=0; for(int j=0; j<=w; ++j) if(codd(l+j-1,j)) m|=1<<(w-j); return m; }
constexpr int laneOf(int wm){ int r=0; for(int w=1;w<=6;++w) if((wm>>w)&1) r|=1<<(6-w); return r; }
constexpr int jOf(int wm){ int r=0; for(int w=7;w<=11;++w) if((wm>>w)&1) r|=1<<(11-w); return r; }
constexpr int hbit(int m){ int h=0; while(m>>(h+1)) ++h; return 1<<h; }

__device__ __forceinline__ v2f vsplat(float s){ v2f v; v.x=s; v.y=s; return v; }
__device__ __forceinline__ v2f vswap(v2f v){ return __builtin_shufflevector(v, v, 1, 0); }
template<int S> __device__ __forceinline__ v2f msw(v2f v){ if constexpr (S) return vswap(v); else return v; }
__device__ __forceinline__ v2f vfma(v2f a, v2f b, v2f c){ return __builtin_elementwise_fma(a,b,c); }

// RX update: re' = hc*r + hs*sw(pi); im' = hc*i - hs*sw(pr)
template<int S>
__device__ __forceinline__ void rx_upd(v2f& ro, v2f& io, v2f r, v2f i, v2f pr, v2f pi,
                                       v2f hc2, v2f hs2, v2f ns2){
    ro = vfma(hc2, r, hs2*msw<S>(pi));
    io = vfma(hc2, i, ns2*msw<S>(pr));
}

#if __has_builtin(__builtin_amdgcn_permlane32_swap) && __has_builtin(__builtin_amdgcn_permlane16_swap)
#define HAVE_PLSWAP 1
#else
#define HAVE_PLSWAP 0
#endif

// ---- DPP lane-xor (VALU pipe), LM in [1,15] (R5-proven) ----
template<int CTRL>
__device__ __forceinline__ float dpp1(float v){
    int i = __float_as_int(v);
    return __int_as_float(__builtin_amdgcn_update_dpp(i, i, CTRL, 0xF, 0xF, true));
}
template<int LM>
__device__ __forceinline__ float dppx(float v){
    static_assert(LM >= 1 && LM <= 15, "dpp xor range");
    constexpr int h = (LM >> 2) & 3;
    float r = v;
    if constexpr (h == 1 || h == 2) r = dpp1<0x141>(r);   // row_half_mirror = xor 7
    if constexpr (h == 3 || h == 2) r = dpp1<0x140>(r);   // row_mirror      = xor 15
    constexpr int st = (h==1)?7 : (h==2)?8 : (h==3)?15 : 0;
    constexpr int q = (LM ^ st) & 3;
    if constexpr (q == 1) r = dpp1<0xB1>(r);              // quad_perm xor 1
    if constexpr (q == 2) r = dpp1<0x4E>(r);              // quad_perm xor 2
    if constexpr (q == 3) r = dpp1<0x1B>(r);              // quad_perm xor 3
    return r;
}

#if HAVE_PLSWAP
// permlane32_swap(a,b) -> {(a_lo,b_lo), (a_hi,b_hi)} (LLVM: ret[0]=vdst', ret[1]=vsrc').
// c1 = swap(r,i); c2 = swap(c1[1], c1[0]) ->
//   c2[0] = (c1[1]_lo, c1[0]_lo) = (r_hi, r_lo) = xor32(r)
//   c2[1] = (c1[1]_hi, c1[0]_hi) = (i_hi, i_lo) = xor32(i)
__device__ __forceinline__ void xp32(float& pr, float& pi, float r, float i){
    auto c1 = __builtin_amdgcn_permlane32_swap(__float_as_uint(r), __float_as_uint(i), false, false);
    auto c2 = __builtin_amdgcn_permlane32_swap(c1[1], c1[0], false, false);
    pr = __uint_as_float(c2[0]);
    pi = __uint_as_float(c2[1]);
}
// same identity with 16-lane rows -> xor16 on both values
__device__ __forceinline__ void xp16(float& pr, float& pi, float r, float i){
    auto c1 = __builtin_amdgcn_permlane16_swap(__float_as_uint(r), __float_as_uint(i), false, false);
    auto c2 = __builtin_amdgcn_permlane16_swap(c1[1], c1[0], false, false);
    pr = __uint_as_float(c2[0]);
    pi = __uint_as_float(c2[1]);
}
#endif

// partner under lane-xor LM for a (re,im) scalar pair.
template<int LM>
__device__ __forceinline__ void lane_partner(float& pr, float& pi, float r, float i, int lane){
#if HAVE_PLSWAP
    float a = r, b = i;
    if constexpr (LM & 32) xp32(a, b, a, b);
    if constexpr (LM & 16) xp16(a, b, a, b);
    if constexpr (LM & 15){ a = dppx<LM&15>(a); b = dppx<LM&15>(b); }
    pr = a; pi = b;
#else
    if constexpr ((LM & 48) != 0){   // fallback: R5-proven ds_bpermute
        const int addr = ((lane ^ LM) & 63) << 2;
        pr = __int_as_float(__builtin_amdgcn_ds_bpermute(addr, __float_as_int(r)));
        pi = __int_as_float(__builtin_amdgcn_ds_bpermute(addr, __float_as_int(i)));
    } else {
        pr = dppx<LM>(r); pi = dppx<LM>(i);
    }
#endif
}
template<int LM>
__device__ __forceinline__ void lane_partner2(v2f& pr, v2f& pi, v2f r, v2f i, int lane){
    float prx, pix, pry, piy;
    lane_partner<LM>(prx, pix, r.x, i.x, lane);
    lane_partner<LM>(pry, piy, r.y, i.y, lane);
    pr.x = prx; pr.y = pry;
    pi.x = pix; pi.y = piy;
}

// ---- RX, partner fully local ----
template<int JM>
__device__ __forceinline__ void rx_local(v2f (&re2)[16], v2f (&im2)[16], v2f hc2, v2f hs2, v2f ns2){
    if constexpr (JM == 1){
        #pragma unroll
        for (int t=0;t<16;++t){
            v2f r=re2[t], i=im2[t];
            rx_upd<1>(re2[t], im2[t], r, i, r, i, hc2, hs2, ns2);
        }
    } else {
        constexpr int m = JM>>1, HB = hbit(m), S = JM&1;
        #pragma unroll
        for (int t=0;t<16;++t){
            if (t & HB) continue;
            const int t2 = t ^ m;
            v2f ru=re2[t], iu=im2[t], rv=re2[t2], iv=im2[t2];
            rx_upd<S>(re2[t],  im2[t],  ru, iu, rv, iv, hc2, hs2, ns2);
            rx_upd<S>(re2[t2], im2[t2], rv, iv, ru, iu, hc2, hs2, ns2);
        }
    }
}

// ---- RX, any lane-crossing (wires1..6), VALU pipe (or bperm fallback) ----
template<int LM,int JM>
__device__ __forceinline__ void rx_lane(v2f (&re2)[16], v2f (&im2)[16], v2f hc2, v2f hs2, v2f ns2,
                                        int lane){
    constexpr int S = JM&1, m = JM>>1;
    if constexpr (m == 0){
        #pragma unroll
        for (int t=0;t<16;++t){
            v2f pr, pi;
            lane_partner2<LM>(pr, pi, re2[t], im2[t], lane);
            rx_upd<S>(re2[t], im2[t], re2[t], im2[t], pr, pi, hc2, hs2, ns2);
        }
    } else {
        constexpr int HB = hbit(m);
        #pragma unroll
        for (int t=0;t<16;++t){
            if (t & HB) continue;
            const int t2 = t ^ m;
            v2f ru=re2[t], iu=im2[t], rv=re2[t2], iv=im2[t2];
            v2f pru, piu, prv, piv;
            lane_partner2<LM>(pru, piu, rv, iv, lane);
            lane_partner2<LM>(prv, piv, ru, iu, lane);
            rx_upd<S>(re2[t],  im2[t],  ru, iu, pru, piu, hc2, hs2, ns2);
            rx_upd<S>(re2[t2], im2[t2], rv, iv, prv, piv, hc2, hs2, ns2);
        }
    }
}

// ---- w0 exchange: b128 full-state exchange through LDS ----
// layout: float4 lds4[2(wv)][16(row: 0-7 re, 8-15 im; row u = j in [4u,4u+4))][64(lane)]
__device__ __forceinline__ void exch_write(const v2f (&re2)[16], const v2f (&im2)[16],
                                           int lane, int wv, float4* lds4){
    float4* wr = lds4 + (wv*16)*64 + lane;
    #pragma unroll
    for (int u=0;u<8;++u){
        float4 fr; fr.x=re2[2*u].x; fr.y=re2[2*u].y; fr.z=re2[2*u+1].x; fr.w=re2[2*u+1].y;
        float4 fi; fi.x=im2[2*u].x; fi.y=im2[2*u].y; fi.z=im2[2*u+1].x; fi.w=im2[2*u+1].y;
        wr[u*64]     = fr;
        wr[(8+u)*64] = fi;
    }
}

template<int C> __device__ __forceinline__ float f4e(float4 f){
    if constexpr (C==0) return f.x; else if constexpr (C==1) return f.y;
    else if constexpr (C==2) return f.z; else return f.w;
}

template<int LM,int JM>
__device__ __forceinline__ void exch_read_rx(v2f (&re2)[16], v2f (&im2)[16],
                                             v2f hc2, v2f hs2, v2f ns2,
                                             int lane, int wv, const float4* lds4){
    const float4* rd = lds4 + ((wv^1)*16)*64 + ((lane^LM)&63);
    constexpr int um = JM>>2, cm = JM&3;
    #pragma unroll
    for (int u=0;u<8;++u){
        float4 Fr = rd[(u^um)*64];
        float4 Fi = rd[(8+(u^um))*64];
        v2f prl, pil, prh, pih;
        prl.x = f4e<(0^cm)&3>(Fr); prl.y = f4e<(1^cm)&3>(Fr);
        prh.x = f4e<(2^cm)&3>(Fr); prh.y = f4e<(3^cm)&3>(Fr);
        pil.x = f4e<(0^cm)&3>(Fi); pil.y = f4e<(1^cm)&3>(Fi);
        pih.x = f4e<(2^cm)&3>(Fi); pih.y = f4e<(3^cm)&3>(Fi);
        rx_upd<0>(re2[2*u],   im2[2*u],   re2[2*u],   im2[2*u],   prl, pil, hc2, hs2, ns2);
        rx_upd<0>(re2[2*u+1], im2[2*u+1], re2[2*u+1], im2[2*u+1], prh, pih, hc2, hs2, ns2);
    }
}

// ---- RZ (diagonal) ----
template<int RW>
__device__ __forceinline__ void rz_gate(v2f (&re2)[16], v2f (&im2)[16], float hc, float hs,
                                        int lane, int wv){
    constexpr int LM = laneOf(RW), JM = jOf(RW), WV = RW & 1;
    int par = __popc(lane & LM);
    if constexpr (WV) par ^= wv;
    const float hp = (par & 1) ? -hs : hs;
    const float hq = (JM & 1) ? -hp : hp;
    v2f A;  A.x = hp;   A.y = hq;
    v2f nA; nA.x = -hp; nA.y = -hq;
    const v2f hc2 = vsplat(hc);
    constexpr int m = JM >> 1;
    #pragma unroll
    for (int t=0;t<16;++t){
        const bool odd = __builtin_popcount(t & m) & 1;   // compile-time
        const v2f SV = odd ? nA : A;
        const v2f SN = odd ? A : nA;
        v2f r = re2[t], i = im2[t];
        re2[t] = vfma(hc2, r, SV*i);
        im2[t] = vfma(hc2, i, SN*r);
    }
}

// ---- per-layer: w1..w11 (VALU only), then w0 exchange ----
template<int L,int W>
__device__ __forceinline__ void gates_w(v2f (&re2)[16], v2f (&im2)[16],
                                        const float4* __restrict__ tb, int lane, int wv){
    const float4 t = tb[W];
    constexpr int M = Mwire(L,W), LM = laneOf(M), JM = jOf(M);
    static_assert((M & 1) == 0, "w>=1 mask must not touch wire0");
    if constexpr (LM) rx_lane<LM,JM>(re2,im2, vsplat(t.x), vsplat(t.y), vsplat(-t.y), lane);
    else              rx_local<JM>(re2,im2, vsplat(t.x), vsplat(t.y), vsplat(-t.y));
    rz_gate<Rwire(L,W)>(re2,im2, t.z, t.w, lane, wv);
    if constexpr (W+1 < NQ) gates_w<L,W+1>(re2,im2,tb,lane,wv);
}

template<int L>
__device__ __forceinline__ void layer(v2f (&re2)[16], v2f (&im2)[16],
                                      const float4* __restrict__ tbl,
                                      int lane, int wv, float4* lds4){
    const float4* tb = tbl + (L-1)*NQ;
    gates_w<L,1>(re2,im2,tb,lane,wv);            // commuting gates first (VALU)
    const float4 t0 = tb[0];
    exch_write(re2,im2,lane,wv,lds4);
    __syncthreads();
    constexpr int M0 = Mwire(L,0);
    exch_read_rx<laneOf(M0), jOf(M0)>(re2,im2, vsplat(t0.x), vsplat(t0.y), vsplat(-t0.y),
                                      lane, wv, lds4);
    rz_gate<Rwire(L,0)>(re2,im2, t0.z, t0.w, lane, wv);
    __syncthreads();
    if constexpr (L < NLAYERS) layer<L+1>(re2,im2,tbl,lane,wv,lds4);
}

// ---- init RX: w1..w11 via VALU transports, then w0 exchange ----
template<int W>
__device__ __forceinline__ void init_w(v2f (&re2)[16], v2f (&im2)[16],
                                       const float* __restrict__ xb, int lane, int wv){
    float hs, hc;
    __sincosf(xb[W]*1.5707963267948966f, &hs, &hc);
    constexpr int M = 1<<W, LM = laneOf(M), JM = jOf(M);
    if constexpr (LM) rx_lane<LM,JM>(re2,im2, vsplat(hc), vsplat(hs), vsplat(-hs), lane);
    else              rx_local<JM>(re2,im2, vsplat(hc), vsplat(hs), vsplat(-hs));
    if constexpr (W+1 < NQ) init_w<W+1>(re2,im2,xb,lane,wv);
}

__global__ void prep_kernel(const float* __restrict__ P, float4* __restrict__ tbl){
    const int i = threadIdx.x;
    if (i < NLAYERS*NQ){
        float4 v;
        __sincosf(P[2*i]   * 0.5f, &v.y, &v.x);   // RX: (cos, sin)
        __sincosf(P[2*i+1] * 0.5f, &v.w, &v.z);   // RZ: (cos, sin)
        tbl[i] = v;
    }
}

__global__ __launch_bounds__(128, 2) void qnn_kernel(const float* __restrict__ x,
                                                     const float4* __restrict__ tbl,
                                                     const float* __restrict__ Wm,
                                                     float* __restrict__ out)
{
    __shared__ float4 lds4[2*16*64];   // 32 KB
    const int lane = threadIdx.x & 63;
    const int wv   = threadIdx.x >> 6;
    const int b    = blockIdx.x;

    v2f re2[16], im2[16];
    #pragma unroll
    for (int t=0;t<16;++t){ re2[t] = vsplat(0.f); im2[t] = vsplat(0.f); }
    if (threadIdx.x == 0) re2[0].x = 1.0f;

    const float* xb = x + b*NQ;
    init_w<1>(re2, im2, xb, lane, wv);
    {
        float hs0, hc0;
        __sincosf(xb[0]*1.5707963267948966f, &hs0, &hc0);
        exch_write(re2,im2,lane,wv,lds4);
        __syncthreads();
        exch_read_rx<0,0>(re2,im2, vsplat(hc0), vsplat(hs0), vsplat(-hs0), lane, wv, lds4);
        __syncthreads();
    }
    layer<1>(re2, im2, tbl, lane, wv, lds4);

    // ---- PauliZ expvals; final L = P^8 => row_w = e_w ^ e_{w-8} ----
    v2f S = vsplat(0.f), S7 = vsplat(0.f), S8 = vsplat(0.f), S9 = vsplat(0.f), S10 = vsplat(0.f);
    #pragma unroll
    for (int t=0;t<16;++t){
        v2f p2 = __builtin_elementwise_fma(re2[t], re2[t], im2[t]*im2[t]);
        S += p2;
        S7  += (t&8)? -p2 : p2;   // wire 7  (j bit4)
        S8  += (t&4)? -p2 : p2;   // wire 8  (j bit3)
        S9  += (t&2)? -p2 : p2;   // wire 9  (j bit2)
        S10 += (t&1)? -p2 : p2;   // wire 10 (j bit1)
    }
    const float s0   = S.x + S.y;
    const float sw7  = S7.x + S7.y;
    const float sw8  = S8.x + S8.y;
    const float sw9  = S9.x + S9.y;
    const float sw10 = S10.x + S10.y;
    const float sw11 = S.x - S.y;             // wire 11 (j bit0 = component)

    float z[12];
    z[0] = wv ? -s0 : s0;
    #pragma unroll
    for (int w=1; w<=6; ++w) z[w] = ((lane >> (6-w)) & 1) ? -s0 : s0;
    z[7]  = sw7;
    z[8]  = wv            ? -sw8  : sw8;      // ^ wire0
    z[9]  = ((lane>>5)&1) ? -sw9  : sw9;      // ^ wire1
    z[10] = ((lane>>4)&1) ? -sw10 : sw10;     // ^ wire2
    z[11] = ((lane>>3)&1) ? -sw11 : sw11;     // ^ wire3

    #pragma unroll
    for (int m=1; m<64; m<<=1){
        #pragma unroll
        for (int w=0; w<12; ++w) z[w] += __shfl_xor(z[w], m, 64);
    }

    float* sh = (float*)lds4;
    if (lane == 0){
        #pragma unroll
        for (int w=0; w<12; ++w) sh[wv*12 + w] = z[w];
    }
    __syncthreads();
    if (wv == 0){
        float t = 0.f;
        if (lane < 12){
            #pragma unroll
            for (int w=0; w<12; ++w){
                float zz = sh[w] + sh[12+w];
                t = fmaf(zz, Wm[w*12 + lane], t);
            }
            t = fmaxf(t, 0.f);
        }
        #pragma unroll
        for (int m=1; m<16; m<<=1) t += __shfl_xor(t, m, 64);
        if (lane == 0) out[b] = t;
    }
}

extern "C" void kernel_launch(void* const* d_in, const int* in_sizes, int n_in,
                              void* d_out, int out_size, void* d_ws, size_t ws_size,
                              hipStream_t stream) {
    const float* x  = (const float*)d_in[0];
    const float* P  = (const float*)d_in[1];
    const float* Wm = (const float*)d_in[2];
    float* out = (float*)d_out;
    float4* tbl = (float4*)d_ws;   // 96 * 16 B = 1536 B
    prep_kernel<<<1, 128, 0, stream>>>(P, tbl);
    qnn_kernel<<<BATCH, 128, 0, stream>>>(x, tbl, Wm, out);
}

// Round 11
// 88.597 us; speedup vs baseline: 1.1093x; 1.1093x over previous
//
#include <hip/hip_runtime.h>

#define NQ 12
#define NLAYERS 8
#define BATCH 1024

typedef float v2f __attribute__((ext_vector_type(2)));

// ---------------------------------------------------------------------------
// R11: CANONICAL layout with per-layer physical CNOT restore.
// Index p = (wv<<11)|(lane<<5)|j ; wire w <-> bit (11-w):
//   wire0 = wv, wires1..6 = lane bits 5..0, wires7..11 = j bits 4..0.
// Layer = [CNOT ladder permute] then RX/RZ on each wire with CANONICAL masks.
// The ladder's gather map is q = p ^ (p>>1) (integer bit space, wv = MSB):
//   srcLane = lane ^ (lane>>1) ^ (wv<<5)
//   srcJ    = j ^ (j>>1) ^ ((lane&1)<<4)
// Permute rides the per-layer LDS exchange; RX(w0) (partner = flip wv, i.e.
// region wv^1, column srcLane^32) merges into the same exchange. All 8 layers
// share ONE code body -> runtime loop, ~8x smaller code (I-fetch theory: wall
// was pinned ~97us across R5-R10 while pipe balance varied; code ~250KB >> L1I).
// Transport: w1/w2 bperm (DS), w3..6 DPP (VALU), w7..11 register-local.
// SoA packing: j = 2t+k ; re2[t]/im2[t] hold re/im of amps (2t,2t+1).
// ---------------------------------------------------------------------------

constexpr int hbit(int m){ int h=0; while(m>>(h+1)) ++h; return 1<<h; }

__device__ __forceinline__ v2f vsplat(float s){ v2f v; v.x=s; v.y=s; return v; }
__device__ __forceinline__ v2f vswap(v2f v){ return __builtin_shufflevector(v, v, 1, 0); }
template<int S> __device__ __forceinline__ v2f msw(v2f v){ if constexpr (S) return vswap(v); else return v; }
__device__ __forceinline__ v2f vfma(v2f a, v2f b, v2f c){ return __builtin_elementwise_fma(a,b,c); }

// RX update: re' = hc*r + hs*sw(pi); im' = hc*i - hs*sw(pr)
template<int S>
__device__ __forceinline__ void rx_upd(v2f& ro, v2f& io, v2f r, v2f i, v2f pr, v2f pi,
                                       v2f hc2, v2f hs2, v2f ns2){
    ro = vfma(hc2, r, hs2*msw<S>(pi));
    io = vfma(hc2, i, ns2*msw<S>(pr));
}

__device__ __forceinline__ v2f bperm2(int addr, v2f v){
    v2f r;
    r.x = __int_as_float(__builtin_amdgcn_ds_bpermute(addr, __float_as_int(v.x)));
    r.y = __int_as_float(__builtin_amdgcn_ds_bpermute(addr, __float_as_int(v.y)));
    return r;
}

// ---- DPP lane-xor (VALU pipe), LM in [1,15] (R5-proven) ----
template<int CTRL>
__device__ __forceinline__ float dpp1(float v){
    int i = __float_as_int(v);
    return __int_as_float(__builtin_amdgcn_update_dpp(i, i, CTRL, 0xF, 0xF, true));
}
template<int LM>
__device__ __forceinline__ float dppx(float v){
    static_assert(LM >= 1 && LM <= 15, "dpp xor range");
    constexpr int h = (LM >> 2) & 3;
    float r = v;
    if constexpr (h == 1 || h == 2) r = dpp1<0x141>(r);   // row_half_mirror = xor 7
    if constexpr (h == 3 || h == 2) r = dpp1<0x140>(r);   // row_mirror      = xor 15
    constexpr int st = (h==1)?7 : (h==2)?8 : (h==3)?15 : 0;
    constexpr int q = (LM ^ st) & 3;
    if constexpr (q == 1) r = dpp1<0xB1>(r);              // quad_perm xor 1
    if constexpr (q == 2) r = dpp1<0x4E>(r);              // quad_perm xor 2
    if constexpr (q == 3) r = dpp1<0x1B>(r);              // quad_perm xor 3
    return r;
}

// ---- RX, partner fully local (JM = j-space xor mask) ----
template<int JM>
__device__ __forceinline__ void rx_local(v2f (&re2)[16], v2f (&im2)[16], v2f hc2, v2f hs2, v2f ns2){
    if constexpr (JM == 1){
        #pragma unroll
        for (int t=0;t<16;++t){
            v2f r=re2[t], i=im2[t];
            rx_upd<1>(re2[t], im2[t], r, i, r, i, hc2, hs2, ns2);
        }
    } else {
        constexpr int m = JM>>1, HB = hbit(m), S = JM&1;
        #pragma unroll
        for (int t=0;t<16;++t){
            if (t & HB) continue;
            const int t2 = t ^ m;
            v2f ru=re2[t], iu=im2[t], rv=re2[t2], iv=im2[t2];
            rx_upd<S>(re2[t],  im2[t],  ru, iu, rv, iv, hc2, hs2, ns2);
            rx_upd<S>(re2[t2], im2[t2], rv, iv, ru, iu, hc2, hs2, ns2);
        }
    }
}

// ---- canonical RX on wire W (1..11); W=0 handled by exchange paths ----
template<int W>
__device__ __forceinline__ void rx_canon(v2f (&re2)[16], v2f (&im2)[16], float hc, float hs, int lane){
    const v2f hc2 = vsplat(hc), hs2 = vsplat(hs), ns2 = vsplat(-hs);
    if constexpr (W >= 1 && W <= 2){            // lane bits 5/4: ds_bpermute
        const int addr = ((lane ^ (1<<(6-W))) & 63) << 2;
        #pragma unroll
        for (int t=0;t<16;++t){
            v2f r=re2[t], i=im2[t];
            v2f pi = bperm2(addr, i);
            v2f pr = bperm2(addr, r);
            rx_upd<0>(re2[t], im2[t], r, i, pr, pi, hc2, hs2, ns2);
        }
    } else if constexpr (W >= 3 && W <= 6){     // lane bits 3..0: DPP
        constexpr int LM = 1<<(6-W);
        #pragma unroll
        for (int t=0;t<16;++t){
            v2f r=re2[t], i=im2[t];
            v2f pr, pi;
            float a0=dppx<LM>(r.x), a1=dppx<LM>(r.y);
            float b0=dppx<LM>(i.x), b1=dppx<LM>(i.y);
            pr.x=a0; pr.y=a1; pi.x=b0; pi.y=b1;
            rx_upd<0>(re2[t], im2[t], r, i, pr, pi, hc2, hs2, ns2);
        }
    } else {                                    // W 7..11: local
        rx_local<(1<<(11-W))>(re2, im2, hc2, hs2, ns2);
    }
}

// ---- canonical RZ on wire W ----
template<int W>
__device__ __forceinline__ void rz_gate(v2f (&re2)[16], v2f (&im2)[16], float hc, float hs,
                                        int lane, int wv){
    float hp;
    if constexpr (W == 0)      hp = wv ? -hs : hs;
    else if constexpr (W <= 6) hp = ((lane >> (6-W)) & 1) ? -hs : hs;
    else                       hp = hs;
    v2f A;
    if constexpr (W == 11){ A.x = hp; A.y = -hp; } else { A = vsplat(hp); }
    const v2f nA = -A;
    const v2f hc2 = vsplat(hc);
    #pragma unroll
    for (int t=0;t<16;++t){
        bool odd = false;
        if constexpr (W >= 7 && W <= 10) odd = (t >> (10-W)) & 1;   // compile-time
        const v2f SV = odd ? nA : A;
        const v2f SN = odd ? A : nA;
        v2f r = re2[t], i = im2[t];
        re2[t] = vfma(hc2, r, SV*i);
        im2[t] = vfma(hc2, i, SN*r);
    }
}

// ---- LDS exchange write (layout float4 lds4[2(wv)][16(row:0-7 re,8-15 im)][64(lane)]) ----
__device__ __forceinline__ void exch_write(const v2f (&re2)[16], const v2f (&im2)[16],
                                           int lane, int wv, float4* lds4){
    float4* wr = lds4 + (wv*16)*64 + lane;
    #pragma unroll
    for (int u=0;u<8;++u){
        float4 fr; fr.x=re2[2*u].x; fr.y=re2[2*u].y; fr.z=re2[2*u+1].x; fr.w=re2[2*u+1].y;
        float4 fi; fi.x=im2[2*u].x; fi.y=im2[2*u].y; fi.z=im2[2*u+1].x; fi.w=im2[2*u+1].y;
        wr[u*64]     = fr;
        wr[(8+u)*64] = fi;
    }
}

// ---- CNOT-ladder permute gather + RX(w0), fused in one exchange read ----
// self:    region wv,   column srcLane      (q_0 = wv)
// partner: region wv^1, column srcLane^32   (flip wire0 flips q_1 = lane bit5)
// row swizzle: srcRow = gray3(u) ^ ((lane&1)<<2); component map by u parity.
__device__ __forceinline__ void perm_rx0(v2f (&re2)[16], v2f (&im2)[16],
                                         float hc, float hs, int lane, int wv,
                                         const float4* lds4){
    const v2f hc2 = vsplat(hc), hs2 = vsplat(hs), ns2 = vsplat(-hs);
    const int sl = ((lane ^ (lane>>1)) & 63) ^ (wv<<5);
    const int rb = (lane & 1) << 2;
    const float4* rdS = lds4 + (wv*16)*64 + sl;
    const float4* rdP = lds4 + ((wv^1)*16)*64 + (sl^32);
    #pragma unroll
    for (int u=0;u<8;++u){
        const int row = (u ^ (u>>1)) ^ rb;
        float4 Fr = rdS[row*64], Fi = rdS[(row+8)*64];
        float4 Gr = rdP[row*64], Gi = rdP[(row+8)*64];
        v2f ar,ai,br,bi, pr,pi,qr,qi;
        if ((u & 1) == 0){   // dest (k0..k3) <- src (x,y,w,z)
            ar.x=Fr.x; ar.y=Fr.y;  br.x=Fr.w; br.y=Fr.z;
            ai.x=Fi.x; ai.y=Fi.y;  bi.x=Fi.w; bi.y=Fi.z;
            pr.x=Gr.x; pr.y=Gr.y;  qr.x=Gr.w; qr.y=Gr.z;
            pi.x=Gi.x; pi.y=Gi.y;  qi.x=Gi.w; qi.y=Gi.z;
        } else {             // dest (k0..k3) <- src (z,w,y,x)
            ar.x=Fr.z; ar.y=Fr.w;  br.x=Fr.y; br.y=Fr.x;
            ai.x=Fi.z; ai.y=Fi.w;  bi.x=Fi.y; bi.y=Fi.x;
            pr.x=Gr.z; pr.y=Gr.w;  qr.x=Gr.y; qr.y=Gr.x;
            pi.x=Gi.z; pi.y=Gi.w;  qi.x=Gi.y; qi.y=Gi.x;
        }
        rx_upd<0>(re2[2*u],   im2[2*u],   ar, ai, pr, pi, hc2, hs2, ns2);
        rx_upd<0>(re2[2*u+1], im2[2*u+1], br, bi, qr, qi, hc2, hs2, ns2);
    }
}

// ---- init-time RX(w0): plain cross-wave exchange (no permute) ----
__device__ __forceinline__ void init_rx0(v2f (&re2)[16], v2f (&im2)[16],
                                         float hc, float hs, int lane, int wv, float4* lds4){
    const v2f hc2 = vsplat(hc), hs2 = vsplat(hs), ns2 = vsplat(-hs);
    exch_write(re2, im2, lane, wv, lds4);
    __syncthreads();
    const float4* rd = lds4 + ((wv^1)*16)*64 + lane;
    #pragma unroll
    for (int u=0;u<8;++u){
        float4 Fr = rd[u*64], Fi = rd[(u+8)*64];
        v2f prl,pil,prh,pih;
        prl.x=Fr.x; prl.y=Fr.y; prh.x=Fr.z; prh.y=Fr.w;
        pil.x=Fi.x; pil.y=Fi.y; pih.x=Fi.z; pih.y=Fi.w;
        rx_upd<0>(re2[2*u],   im2[2*u],   re2[2*u],   im2[2*u],   prl, pil, hc2, hs2, ns2);
        rx_upd<0>(re2[2*u+1], im2[2*u+1], re2[2*u+1], im2[2*u+1], prh, pih, hc2, hs2, ns2);
    }
    __syncthreads();
}

// ---- per-layer gates w1..w11 (canonical masks, layer-independent code) ----
template<int W>
__device__ __forceinline__ void gates_w(v2f (&re2)[16], v2f (&im2)[16],
                                        const float4* __restrict__ tb, int lane, int wv){
    const float4 t = tb[W];
    rx_canon<W>(re2, im2, t.x, t.y, lane);
    rz_gate<W>(re2, im2, t.z, t.w, lane, wv);
    if constexpr (W+1 < NQ) gates_w<W+1>(re2, im2, tb, lane, wv);
}

// ---- init RX w1..w11 ----
template<int W>
__device__ __forceinline__ void init_w(v2f (&re2)[16], v2f (&im2)[16],
                                       const float* __restrict__ xb, int lane){
    float hs, hc;
    __sincosf(xb[W]*1.5707963267948966f, &hs, &hc);
    rx_canon<W>(re2, im2, hc, hs, lane);
    if constexpr (W+1 < NQ) init_w<W+1>(re2, im2, xb, lane);
}

__global__ void prep_kernel(const float* __restrict__ P, float4* __restrict__ tbl){
    const int i = threadIdx.x;
    if (i < NLAYERS*NQ){
        float4 v;
        __sincosf(P[2*i]   * 0.5f, &v.y, &v.x);   // RX: (cos, sin)
        __sincosf(P[2*i+1] * 0.5f, &v.w, &v.z);   // RZ: (cos, sin)
        tbl[i] = v;
    }
}

__global__ __launch_bounds__(128, 2) void qnn_kernel(const float* __restrict__ x,
                                                     const float4* __restrict__ tbl,
                                                     const float* __restrict__ Wm,
                                                     float* __restrict__ out)
{
    __shared__ float4 lds4[2*16*64];   // 32 KB
    const int lane = threadIdx.x & 63;
    const int wv   = threadIdx.x >> 6;
    const int b    = blockIdx.x;

    v2f re2[16], im2[16];
    #pragma unroll
    for (int t=0;t<16;++t){ re2[t] = vsplat(0.f); im2[t] = vsplat(0.f); }
    if (threadIdx.x == 0) re2[0].x = 1.0f;

    const float* xb = x + b*NQ;
    init_w<1>(re2, im2, xb, lane);
    {
        float hs0, hc0;
        __sincosf(xb[0]*1.5707963267948966f, &hs0, &hc0);
        init_rx0(re2, im2, hc0, hs0, lane, wv, lds4);
    }

    #pragma unroll 1
    for (int l = 0; l < NLAYERS; ++l){
        const float4* tb = tbl + l*NQ;
        const float4 t0 = tb[0];
        exch_write(re2, im2, lane, wv, lds4);
        __syncthreads();
        perm_rx0(re2, im2, t0.x, t0.y, lane, wv, lds4);
        rz_gate<0>(re2, im2, t0.z, t0.w, lane, wv);
        gates_w<1>(re2, im2, tb, lane, wv);
        __syncthreads();
    }

    // ---- PauliZ expvals (state is CANONICAL after per-layer restore) ----
    v2f S = vsplat(0.f), S7 = vsplat(0.f), S8 = vsplat(0.f), S9 = vsplat(0.f), S10 = vsplat(0.f);
    #pragma unroll
    for (int t=0;t<16;++t){
        v2f p2 = __builtin_elementwise_fma(re2[t], re2[t], im2[t]*im2[t]);
        S += p2;
        S7  += (t&8)? -p2 : p2;   // wire 7  (j bit4)
        S8  += (t&4)? -p2 : p2;   // wire 8  (j bit3)
        S9  += (t&2)? -p2 : p2;   // wire 9  (j bit2)
        S10 += (t&1)? -p2 : p2;   // wire 10 (j bit1)
    }
    const float s0 = S.x + S.y;

    float z[12];
    z[0] = wv ? -s0 : s0;
    #pragma unroll
    for (int w=1; w<=6; ++w) z[w] = ((lane >> (6-w)) & 1) ? -s0 : s0;
    z[7]  = S7.x + S7.y;
    z[8]  = S8.x + S8.y;
    z[9]  = S9.x + S9.y;
    z[10] = S10.x + S10.y;
    z[11] = S.x - S.y;            // wire 11 (j bit0 = component)

    #pragma unroll
    for (int m=1; m<64; m<<=1){
        #pragma unroll
        for (int w=0; w<12; ++w) z[w] += __shfl_xor(z[w], m, 64);
    }

    float* sh = (float*)lds4;
    if (lane == 0){
        #pragma unroll
        for (int w=0; w<12; ++w) sh[wv*12 + w] = z[w];
    }
    __syncthreads();
    if (wv == 0){
        float t = 0.f;
        if (lane < 12){
            #pragma unroll
            for (int w=0; w<12; ++w){
                float zz = sh[w] + sh[12+w];
                t = fmaf(zz, Wm[w*12 + lane], t);
            }
            t = fmaxf(t, 0.f);
        }
        #pragma unroll
        for (int m=1; m<16; m<<=1) t += __shfl_xor(t, m, 64);
        if (lane == 0) out[b] = t;
    }
}

extern "C" void kernel_launch(void* const* d_in, const int* in_sizes, int n_in,
                              void* d_out, int out_size, void* d_ws, size_t ws_size,
                              hipStream_t stream) {
    const float* x  = (const float*)d_in[0];
    const float* P  = (const float*)d_in[1];
    const float* Wm = (const float*)d_in[2];
    float* out = (float*)d_out;
    float4* tbl = (float4*)d_ws;   // 96 * 16 B = 1536 B
    prep_kernel<<<1, 128, 0, stream>>>(P, tbl);
    qnn_kernel<<<BATCH, 128, 0, stream>>>(x, tbl, Wm, out);
}

// Round 12
// 71.966 us; speedup vs baseline: 1.3656x; 1.2311x over previous
//
#include <hip/hip_runtime.h>

#define NQ 12
#define NLAYERS 8
#define BATCH 1024

typedef float v2f __attribute__((ext_vector_type(2)));

// ---------------------------------------------------------------------------
// R12 = R11 (canonical layout + per-layer physical CNOT restore riding the
// LDS exchange; runtime layer loop -> small code, I-fetch fixed) + FUSED RZ:
// all 12 RZ of a layer hoisted after the 12 RX (distinct wires commute) and
// applied as ONE diagonal: phase(p) = e^{i a(wv,lane)} * e^{i b(j)}.
//   a = sum_{w=0..6} +-th_w/2  (signs from wv/lane bits; one sincos per lane)
//   b_j = sum_{w=7..11} +-th_w/2 (32 values, PRECOMPUTED per layer in prep ->
//         wave-uniform float4 table, SGPR loads)
// Index p = (wv<<11)|(lane<<5)|j ; wire w <-> bit (11-w):
//   wire0 = wv, wires1..6 = lane bits 5..0, wires7..11 = j bits 4..0.
// CNOT ladder gather: q = p ^ (p>>1): srcLane = lane^(lane>>1)^(wv<<5),
//   srcJ = j^(j>>1)^((lane&1)<<4); fused with RX(w0) in the exchange read.
// Transport: w1/w2 bperm (DS), w3..6 DPP (VALU), w7..11 register-local.
// SoA packing: j = 2t+k ; re2[t]/im2[t] hold re/im of amps (2t,2t+1).
// ---------------------------------------------------------------------------

constexpr int hbit(int m){ int h=0; while(m>>(h+1)) ++h; return 1<<h; }

__device__ __forceinline__ v2f vsplat(float s){ v2f v; v.x=s; v.y=s; return v; }
__device__ __forceinline__ v2f vswap(v2f v){ return __builtin_shufflevector(v, v, 1, 0); }
template<int S> __device__ __forceinline__ v2f msw(v2f v){ if constexpr (S) return vswap(v); else return v; }
__device__ __forceinline__ v2f vfma(v2f a, v2f b, v2f c){ return __builtin_elementwise_fma(a,b,c); }

// RX update: re' = hc*r + hs*sw(pi); im' = hc*i - hs*sw(pr)
template<int S>
__device__ __forceinline__ void rx_upd(v2f& ro, v2f& io, v2f r, v2f i, v2f pr, v2f pi,
                                       v2f hc2, v2f hs2, v2f ns2){
    ro = vfma(hc2, r, hs2*msw<S>(pi));
    io = vfma(hc2, i, ns2*msw<S>(pr));
}

__device__ __forceinline__ v2f bperm2(int addr, v2f v){
    v2f r;
    r.x = __int_as_float(__builtin_amdgcn_ds_bpermute(addr, __float_as_int(v.x)));
    r.y = __int_as_float(__builtin_amdgcn_ds_bpermute(addr, __float_as_int(v.y)));
    return r;
}

// ---- DPP lane-xor (VALU pipe), LM in [1,15] (R5-proven) ----
template<int CTRL>
__device__ __forceinline__ float dpp1(float v){
    int i = __float_as_int(v);
    return __int_as_float(__builtin_amdgcn_update_dpp(i, i, CTRL, 0xF, 0xF, true));
}
template<int LM>
__device__ __forceinline__ float dppx(float v){
    static_assert(LM >= 1 && LM <= 15, "dpp xor range");
    constexpr int h = (LM >> 2) & 3;
    float r = v;
    if constexpr (h == 1 || h == 2) r = dpp1<0x141>(r);   // row_half_mirror = xor 7
    if constexpr (h == 3 || h == 2) r = dpp1<0x140>(r);   // row_mirror      = xor 15
    constexpr int st = (h==1)?7 : (h==2)?8 : (h==3)?15 : 0;
    constexpr int q = (LM ^ st) & 3;
    if constexpr (q == 1) r = dpp1<0xB1>(r);              // quad_perm xor 1
    if constexpr (q == 2) r = dpp1<0x4E>(r);              // quad_perm xor 2
    if constexpr (q == 3) r = dpp1<0x1B>(r);              // quad_perm xor 3
    return r;
}

// ---- RX, partner fully local (JM = j-space xor mask) ----
template<int JM>
__device__ __forceinline__ void rx_local(v2f (&re2)[16], v2f (&im2)[16], v2f hc2, v2f hs2, v2f ns2){
    if constexpr (JM == 1){
        #pragma unroll
        for (int t=0;t<16;++t){
            v2f r=re2[t], i=im2[t];
            rx_upd<1>(re2[t], im2[t], r, i, r, i, hc2, hs2, ns2);
        }
    } else {
        constexpr int m = JM>>1, HB = hbit(m), S = JM&1;
        #pragma unroll
        for (int t=0;t<16;++t){
            if (t & HB) continue;
            const int t2 = t ^ m;
            v2f ru=re2[t], iu=im2[t], rv=re2[t2], iv=im2[t2];
            rx_upd<S>(re2[t],  im2[t],  ru, iu, rv, iv, hc2, hs2, ns2);
            rx_upd<S>(re2[t2], im2[t2], rv, iv, ru, iu, hc2, hs2, ns2);
        }
    }
}

// ---- canonical RX on wire W (1..11); W=0 handled by exchange paths ----
template<int W>
__device__ __forceinline__ void rx_canon(v2f (&re2)[16], v2f (&im2)[16], float hc, float hs, int lane){
    const v2f hc2 = vsplat(hc), hs2 = vsplat(hs), ns2 = vsplat(-hs);
    if constexpr (W >= 1 && W <= 2){            // lane bits 5/4: ds_bpermute
        const int addr = ((lane ^ (1<<(6-W))) & 63) << 2;
        #pragma unroll
        for (int t=0;t<16;++t){
            v2f r=re2[t], i=im2[t];
            v2f pi = bperm2(addr, i);
            v2f pr = bperm2(addr, r);
            rx_upd<0>(re2[t], im2[t], r, i, pr, pi, hc2, hs2, ns2);
        }
    } else if constexpr (W >= 3 && W <= 6){     // lane bits 3..0: DPP
        constexpr int LM = 1<<(6-W);
        #pragma unroll
        for (int t=0;t<16;++t){
            v2f r=re2[t], i=im2[t];
            v2f pr, pi;
            float a0=dppx<LM>(r.x), a1=dppx<LM>(r.y);
            float b0=dppx<LM>(i.x), b1=dppx<LM>(i.y);
            pr.x=a0; pr.y=a1; pi.x=b0; pi.y=b1;
            rx_upd<0>(re2[t], im2[t], r, i, pr, pi, hc2, hs2, ns2);
        }
    } else {                                    // W 7..11: local
        rx_local<(1<<(11-W))>(re2, im2, hc2, hs2, ns2);
    }
}

// ---- LDS exchange write (layout float4 lds4[2(wv)][16(row:0-7 re,8-15 im)][64(lane)]) ----
__device__ __forceinline__ void exch_write(const v2f (&re2)[16], const v2f (&im2)[16],
                                           int lane, int wv, float4* lds4){
    float4* wr = lds4 + (wv*16)*64 + lane;
    #pragma unroll
    for (int u=0;u<8;++u){
        float4 fr; fr.x=re2[2*u].x; fr.y=re2[2*u].y; fr.z=re2[2*u+1].x; fr.w=re2[2*u+1].y;
        float4 fi; fi.x=im2[2*u].x; fi.y=im2[2*u].y; fi.z=im2[2*u+1].x; fi.w=im2[2*u+1].y;
        wr[u*64]     = fr;
        wr[(8+u)*64] = fi;
    }
}

// ---- CNOT-ladder permute gather + RX(w0), fused in one exchange read (R11-verified) ----
__device__ __forceinline__ void perm_rx0(v2f (&re2)[16], v2f (&im2)[16],
                                         float hc, float hs, int lane, int wv,
                                         const float4* lds4){
    const v2f hc2 = vsplat(hc), hs2 = vsplat(hs), ns2 = vsplat(-hs);
    const int sl = ((lane ^ (lane>>1)) & 63) ^ (wv<<5);
    const int rb = (lane & 1) << 2;
    const float4* rdS = lds4 + (wv*16)*64 + sl;
    const float4* rdP = lds4 + ((wv^1)*16)*64 + (sl^32);
    #pragma unroll
    for (int u=0;u<8;++u){
        const int row = (u ^ (u>>1)) ^ rb;
        float4 Fr = rdS[row*64], Fi = rdS[(row+8)*64];
        float4 Gr = rdP[row*64], Gi = rdP[(row+8)*64];
        v2f ar,ai,br,bi, pr,pi,qr,qi;
        if ((u & 1) == 0){   // dest (k0..k3) <- src (x,y,w,z)
            ar.x=Fr.x; ar.y=Fr.y;  br.x=Fr.w; br.y=Fr.z;
            ai.x=Fi.x; ai.y=Fi.y;  bi.x=Fi.w; bi.y=Fi.z;
            pr.x=Gr.x; pr.y=Gr.y;  qr.x=Gr.w; qr.y=Gr.z;
            pi.x=Gi.x; pi.y=Gi.y;  qi.x=Gi.w; qi.y=Gi.z;
        } else {             // dest (k0..k3) <- src (z,w,y,x)
            ar.x=Fr.z; ar.y=Fr.w;  br.x=Fr.y; br.y=Fr.x;
            ai.x=Fi.z; ai.y=Fi.w;  bi.x=Fi.y; bi.y=Fi.x;
            pr.x=Gr.z; pr.y=Gr.w;  qr.x=Gr.y; qr.y=Gr.x;
            pi.x=Gi.z; pi.y=Gi.w;  qi.x=Gi.y; qi.y=Gi.x;
        }
        rx_upd<0>(re2[2*u],   im2[2*u],   ar, ai, pr, pi, hc2, hs2, ns2);
        rx_upd<0>(re2[2*u+1], im2[2*u+1], br, bi, qr, qi, hc2, hs2, ns2);
    }
}

// ---- init-time RX(w0): plain cross-wave exchange (no permute) ----
__device__ __forceinline__ void init_rx0(v2f (&re2)[16], v2f (&im2)[16],
                                         float hc, float hs, int lane, int wv, float4* lds4){
    const v2f hc2 = vsplat(hc), hs2 = vsplat(hs), ns2 = vsplat(-hs);
    exch_write(re2, im2, lane, wv, lds4);
    __syncthreads();
    const float4* rd = lds4 + ((wv^1)*16)*64 + lane;
    #pragma unroll
    for (int u=0;u<8;++u){
        float4 Fr = rd[u*64], Fi = rd[(u+8)*64];
        v2f prl,pil,prh,pih;
        prl.x=Fr.x; prl.y=Fr.y; prh.x=Fr.z; prh.y=Fr.w;
        pil.x=Fi.x; pil.y=Fi.y; pih.x=Fi.z; pih.y=Fi.w;
        rx_upd<0>(re2[2*u],   im2[2*u],   re2[2*u],   im2[2*u],   prl, pil, hc2, hs2, ns2);
        rx_upd<0>(re2[2*u+1], im2[2*u+1], re2[2*u+1], im2[2*u+1], prh, pih, hc2, hs2, ns2);
    }
    __syncthreads();
}

// ---- per-layer RX gates w1..w11 (canonical masks) ----
template<int W>
__device__ __forceinline__ void gates_w(v2f (&re2)[16], v2f (&im2)[16],
                                        const float2* __restrict__ tb, int lane){
    const float2 t = tb[W];
    rx_canon<W>(re2, im2, t.x, t.y, lane);
    if constexpr (W+1 < NQ) gates_w<W+1>(re2, im2, tb, lane);
}

// ---- init RX w1..w11 ----
template<int W>
__device__ __forceinline__ void init_w(v2f (&re2)[16], v2f (&im2)[16],
                                       const float* __restrict__ xb, int lane){
    float hs, hc;
    __sincosf(xb[W]*1.5707963267948966f, &hs, &hc);
    rx_canon<W>(re2, im2, hc, hs, lane);
    if constexpr (W+1 < NQ) init_w<W+1>(re2, im2, xb, lane);
}

// ---------------------------------------------------------------------------
// Workspace layout (floats): [0,192) tRX float2[8][12] (cos,sin of RX th/2)
//                            [192,256) tTH float[8][8] (RZ th/2, w=0..6)
//                            [256,768) tJ float4[8][16] (cos b_{2t}, cos b_{2t+1},
//                                                        sin b_{2t}, sin b_{2t+1})
// ---------------------------------------------------------------------------
__global__ void prep_kernel(const float* __restrict__ P, float* __restrict__ ws){
    const int i = threadIdx.x;   // 128 threads
    float2* tRX = (float2*)ws;
    float*  tTH = ws + 192;
    float4* tJ  = (float4*)(ws + 256);
    if (i < 96){
        const int l = i/12, w = i%12;
        float2 v; __sincosf(P[l*24 + 2*w]*0.5f, &v.y, &v.x);
        tRX[i] = v;
    }
    if (i < 64){
        const int l = i>>3, w = i&7;
        tTH[i] = (w < 7) ? P[l*24 + 2*w + 1]*0.5f : 0.f;
    }
    {
        const int l = i>>4, t = i&15;
        float br[2], bi[2];
        #pragma unroll
        for (int k=0;k<2;++k){
            const int j = 2*t + k;
            float beta = 0.f;
            #pragma unroll
            for (int w=7; w<12; ++w){
                const float th = P[l*24 + 2*w + 1]*0.5f;
                beta += ((j >> (11-w)) & 1) ? th : -th;
            }
            __sincosf(beta, &bi[k], &br[k]);
        }
        float4 v; v.x=br[0]; v.y=br[1]; v.z=bi[0]; v.w=bi[1];
        tJ[i] = v;
    }
}

__global__ __launch_bounds__(128, 2) void qnn_kernel(const float* __restrict__ x,
                                                     const float* __restrict__ ws,
                                                     const float* __restrict__ Wm,
                                                     float* __restrict__ out)
{
    __shared__ float4 lds4[2*16*64];   // 32 KB
    const int lane = threadIdx.x & 63;
    const int wv   = threadIdx.x >> 6;
    const int b    = blockIdx.x;

    const float2* tRX = (const float2*)ws;
    const float*  tTH = ws + 192;
    const float4* tJ  = (const float4*)(ws + 256);

    v2f re2[16], im2[16];
    #pragma unroll
    for (int t=0;t<16;++t){ re2[t] = vsplat(0.f); im2[t] = vsplat(0.f); }
    if (threadIdx.x == 0) re2[0].x = 1.0f;

    const float* xb = x + b*NQ;
    init_w<1>(re2, im2, xb, lane);
    {
        float hs0, hc0;
        __sincosf(xb[0]*1.5707963267948966f, &hs0, &hc0);
        init_rx0(re2, im2, hc0, hs0, lane, wv, lds4);
    }

    #pragma unroll 1
    for (int l = 0; l < NLAYERS; ++l){
        const float2* tb = tRX + l*12;
        const float2 t0 = tb[0];
        exch_write(re2, im2, lane, wv, lds4);
        __syncthreads();
        perm_rx0(re2, im2, t0.x, t0.y, lane, wv, lds4);      // CNOT restore + RX(w0)
        gates_w<1>(re2, im2, tb, lane);                      // RX w1..w11

        // ---- fused RZ (all 12 wires) ----
        const float* th = tTH + l*8;
        float alpha = wv ? th[0] : -th[0];
        #pragma unroll
        for (int w=1; w<=6; ++w)
            alpha += ((lane >> (6-w)) & 1) ? th[w] : -th[w];
        float sa, ca;
        __sincosf(alpha, &sa, &ca);
        const v2f vca = vsplat(ca), vsa = vsplat(sa), vna = vsplat(-sa);
        const float4* tj = tJ + l*16;
        #pragma unroll
        for (int t=0;t<16;++t){
            const float4 J = tj[t];
            v2f jr; jr.x=J.x; jr.y=J.y;
            v2f ji; ji.x=J.z; ji.y=J.w;
            const v2f cr = vfma(vca, jr, vna*ji);   // cos(a+b) pair
            const v2f ci = vfma(vca, ji, vsa*jr);   // sin(a+b) pair
            const v2f nci = -ci;
            const v2f r = re2[t], m = im2[t];
            re2[t] = vfma(r, cr, m*nci);
            im2[t] = vfma(m, cr, r*ci);
        }
        __syncthreads();
    }

    // ---- PauliZ expvals (state is CANONICAL after per-layer restore) ----
    v2f S = vsplat(0.f), S7 = vsplat(0.f), S8 = vsplat(0.f), S9 = vsplat(0.f), S10 = vsplat(0.f);
    #pragma unroll
    for (int t=0;t<16;++t){
        v2f p2 = __builtin_elementwise_fma(re2[t], re2[t], im2[t]*im2[t]);
        S += p2;
        S7  += (t&8)? -p2 : p2;   // wire 7  (j bit4)
        S8  += (t&4)? -p2 : p2;   // wire 8  (j bit3)
        S9  += (t&2)? -p2 : p2;   // wire 9  (j bit2)
        S10 += (t&1)? -p2 : p2;   // wire 10 (j bit1)
    }
    const float s0 = S.x + S.y;

    float z[12];
    z[0] = wv ? -s0 : s0;
    #pragma unroll
    for (int w=1; w<=6; ++w) z[w] = ((lane >> (6-w)) & 1) ? -s0 : s0;
    z[7]  = S7.x + S7.y;
    z[8]  = S8.x + S8.y;
    z[9]  = S9.x + S9.y;
    z[10] = S10.x + S10.y;
    z[11] = S.x - S.y;            // wire 11 (j bit0 = component)

    #pragma unroll
    for (int m=1; m<64; m<<=1){
        #pragma unroll
        for (int w=0; w<12; ++w) z[w] += __shfl_xor(z[w], m, 64);
    }

    float* sh = (float*)lds4;
    if (lane == 0){
        #pragma unroll
        for (int w=0; w<12; ++w) sh[wv*12 + w] = z[w];
    }
    __syncthreads();
    if (wv == 0){
        float t = 0.f;
        if (lane < 12){
            #pragma unroll
            for (int w=0; w<12; ++w){
                float zz = sh[w] + sh[12+w];
                t = fmaf(zz, Wm[w*12 + lane], t);
            }
            t = fmaxf(t, 0.f);
        }
        #pragma unroll
        for (int m=1; m<16; m<<=1) t += __shfl_xor(t, m, 64);
        if (lane == 0) out[b] = t;
    }
}

extern "C" void kernel_launch(void* const* d_in, const int* in_sizes, int n_in,
                              void* d_out, int out_size, void* d_ws, size_t ws_size,
                              hipStream_t stream) {
    const float* x  = (const float*)d_in[0];
    const float* P  = (const float*)d_in[1];
    const float* Wm = (const float*)d_in[2];
    float* out = (float*)d_out;
    float* ws  = (float*)d_ws;    // 768 floats = 3 KB
    prep_kernel<<<1, 128, 0, stream>>>(P, ws);
    qnn_kernel<<<BATCH, 128, 0, stream>>>(x, ws, Wm, out);
}

// Round 13
// 71.130 us; speedup vs baseline: 1.3817x; 1.0117x over previous
//
#include <hip/hip_runtime.h>

#define NQ 12
#define NLAYERS 8
#define BATCH 1024

typedef float v2f __attribute__((ext_vector_type(2)));

// ---------------------------------------------------------------------------
// R13 = R12 (canonical layout + per-layer physical CNOT restore riding the
// LDS exchange + fused-RZ diagonal + runtime layer loop) with w1/w2 RX
// transport moved DS->VALU via v_permlane32/16_swap double-swap (R10-verified
// builtins). DS ops/layer/wave: 176 -> 48 (exchange only).
// Index p = (wv<<11)|(lane<<5)|j ; wire w <-> bit (11-w):
//   wire0 = wv, wires1..6 = lane bits 5..0, wires7..11 = j bits 4..0.
// CNOT ladder gather: q = p ^ (p>>1): srcLane = lane^(lane>>1)^(wv<<5),
//   srcJ = j^(j>>1)^((lane&1)<<4); fused with RX(w0) in the exchange read.
// Fused RZ: phase(p) = e^{i a(wv,lane)} * e^{i b(j)}; a via 1 sincos/lane,
//   b_j precomputed per layer in prep (wave-uniform float4 -> SGPR loads).
// Transport: w1/w2 permlane-swap (VALU), w3..6 DPP (VALU), w7..11 local.
// SoA packing: j = 2t+k ; re2[t]/im2[t] hold re/im of amps (2t,2t+1).
// ---------------------------------------------------------------------------

constexpr int hbit(int m){ int h=0; while(m>>(h+1)) ++h; return 1<<h; }

__device__ __forceinline__ v2f vsplat(float s){ v2f v; v.x=s; v.y=s; return v; }
__device__ __forceinline__ v2f vswap(v2f v){ return __builtin_shufflevector(v, v, 1, 0); }
template<int S> __device__ __forceinline__ v2f msw(v2f v){ if constexpr (S) return vswap(v); else return v; }
__device__ __forceinline__ v2f vfma(v2f a, v2f b, v2f c){ return __builtin_elementwise_fma(a,b,c); }

// RX update: re' = hc*r + hs*sw(pi); im' = hc*i - hs*sw(pr)
template<int S>
__device__ __forceinline__ void rx_upd(v2f& ro, v2f& io, v2f r, v2f i, v2f pr, v2f pi,
                                       v2f hc2, v2f hs2, v2f ns2){
    ro = vfma(hc2, r, hs2*msw<S>(pi));
    io = vfma(hc2, i, ns2*msw<S>(pr));
}

__device__ __forceinline__ v2f bperm2(int addr, v2f v){
    v2f r;
    r.x = __int_as_float(__builtin_amdgcn_ds_bpermute(addr, __float_as_int(v.x)));
    r.y = __int_as_float(__builtin_amdgcn_ds_bpermute(addr, __float_as_int(v.y)));
    return r;
}

#if __has_builtin(__builtin_amdgcn_permlane32_swap) && __has_builtin(__builtin_amdgcn_permlane16_swap)
#define HAVE_PLSWAP 1
#else
#define HAVE_PLSWAP 0
#endif

#if HAVE_PLSWAP
// double-swap (R10-verified): c1 = swap(r,i); c2 = swap(c1[1], c1[0]) ->
//   c2[0] = xorK(r), c2[1] = xorK(i)   (convention-independent)
__device__ __forceinline__ void xp32(float& pr, float& pi, float r, float i){
    auto c1 = __builtin_amdgcn_permlane32_swap(__float_as_uint(r), __float_as_uint(i), false, false);
    auto c2 = __builtin_amdgcn_permlane32_swap(c1[1], c1[0], false, false);
    pr = __uint_as_float(c2[0]);
    pi = __uint_as_float(c2[1]);
}
__device__ __forceinline__ void xp16(float& pr, float& pi, float r, float i){
    auto c1 = __builtin_amdgcn_permlane16_swap(__float_as_uint(r), __float_as_uint(i), false, false);
    auto c2 = __builtin_amdgcn_permlane16_swap(c1[1], c1[0], false, false);
    pr = __uint_as_float(c2[0]);
    pi = __uint_as_float(c2[1]);
}
#endif

// ---- DPP lane-xor (VALU pipe), LM in [1,15] (R5-proven) ----
template<int CTRL>
__device__ __forceinline__ float dpp1(float v){
    int i = __float_as_int(v);
    return __int_as_float(__builtin_amdgcn_update_dpp(i, i, CTRL, 0xF, 0xF, true));
}
template<int LM>
__device__ __forceinline__ float dppx(float v){
    static_assert(LM >= 1 && LM <= 15, "dpp xor range");
    constexpr int h = (LM >> 2) & 3;
    float r = v;
    if constexpr (h == 1 || h == 2) r = dpp1<0x141>(r);   // row_half_mirror = xor 7
    if constexpr (h == 3 || h == 2) r = dpp1<0x140>(r);   // row_mirror      = xor 15
    constexpr int st = (h==1)?7 : (h==2)?8 : (h==3)?15 : 0;
    constexpr int q = (LM ^ st) & 3;
    if constexpr (q == 1) r = dpp1<0xB1>(r);              // quad_perm xor 1
    if constexpr (q == 2) r = dpp1<0x4E>(r);              // quad_perm xor 2
    if constexpr (q == 3) r = dpp1<0x1B>(r);              // quad_perm xor 3
    return r;
}

// ---- RX, partner fully local (JM = j-space xor mask) ----
template<int JM>
__device__ __forceinline__ void rx_local(v2f (&re2)[16], v2f (&im2)[16], v2f hc2, v2f hs2, v2f ns2){
    if constexpr (JM == 1){
        #pragma unroll
        for (int t=0;t<16;++t){
            v2f r=re2[t], i=im2[t];
            rx_upd<1>(re2[t], im2[t], r, i, r, i, hc2, hs2, ns2);
        }
    } else {
        constexpr int m = JM>>1, HB = hbit(m), S = JM&1;
        #pragma unroll
        for (int t=0;t<16;++t){
            if (t & HB) continue;
            const int t2 = t ^ m;
            v2f ru=re2[t], iu=im2[t], rv=re2[t2], iv=im2[t2];
            rx_upd<S>(re2[t],  im2[t],  ru, iu, rv, iv, hc2, hs2, ns2);
            rx_upd<S>(re2[t2], im2[t2], rv, iv, ru, iu, hc2, hs2, ns2);
        }
    }
}

// ---- canonical RX on wire W (1..11); W=0 handled by exchange paths ----
template<int W>
__device__ __forceinline__ void rx_canon(v2f (&re2)[16], v2f (&im2)[16], float hc, float hs, int lane){
    const v2f hc2 = vsplat(hc), hs2 = vsplat(hs), ns2 = vsplat(-hs);
    if constexpr (W >= 1 && W <= 2){            // lane bits 5/4
#if HAVE_PLSWAP
        #pragma unroll
        for (int t=0;t<16;++t){
            v2f r=re2[t], i=im2[t];
            float prx,pix,pry,piy;
            if constexpr (W==1){ xp32(prx,pix,r.x,i.x); xp32(pry,piy,r.y,i.y); }
            else               { xp16(prx,pix,r.x,i.x); xp16(pry,piy,r.y,i.y); }
            v2f pr, pi;
            pr.x=prx; pr.y=pry; pi.x=pix; pi.y=piy;
            rx_upd<0>(re2[t], im2[t], r, i, pr, pi, hc2, hs2, ns2);
        }
#else
        const int addr = ((lane ^ (1<<(6-W))) & 63) << 2;
        #pragma unroll
        for (int t=0;t<16;++t){
            v2f r=re2[t], i=im2[t];
            v2f pi = bperm2(addr, i);
            v2f pr = bperm2(addr, r);
            rx_upd<0>(re2[t], im2[t], r, i, pr, pi, hc2, hs2, ns2);
        }
#endif
    } else if constexpr (W >= 3 && W <= 6){     // lane bits 3..0: DPP
        constexpr int LM = 1<<(6-W);
        #pragma unroll
        for (int t=0;t<16;++t){
            v2f r=re2[t], i=im2[t];
            v2f pr, pi;
            float a0=dppx<LM>(r.x), a1=dppx<LM>(r.y);
            float b0=dppx<LM>(i.x), b1=dppx<LM>(i.y);
            pr.x=a0; pr.y=a1; pi.x=b0; pi.y=b1;
            rx_upd<0>(re2[t], im2[t], r, i, pr, pi, hc2, hs2, ns2);
        }
    } else {                                    // W 7..11: local
        rx_local<(1<<(11-W))>(re2, im2, hc2, hs2, ns2);
    }
}

// ---- LDS exchange write (layout float4 lds4[2(wv)][16(row:0-7 re,8-15 im)][64(lane)]) ----
__device__ __forceinline__ void exch_write(const v2f (&re2)[16], const v2f (&im2)[16],
                                           int lane, int wv, float4* lds4){
    float4* wr = lds4 + (wv*16)*64 + lane;
    #pragma unroll
    for (int u=0;u<8;++u){
        float4 fr; fr.x=re2[2*u].x; fr.y=re2[2*u].y; fr.z=re2[2*u+1].x; fr.w=re2[2*u+1].y;
        float4 fi; fi.x=im2[2*u].x; fi.y=im2[2*u].y; fi.z=im2[2*u+1].x; fi.w=im2[2*u+1].y;
        wr[u*64]     = fr;
        wr[(8+u)*64] = fi;
    }
}

// ---- CNOT-ladder permute gather + RX(w0), fused in one exchange read (R11-verified) ----
__device__ __forceinline__ void perm_rx0(v2f (&re2)[16], v2f (&im2)[16],
                                         float hc, float hs, int lane, int wv,
                                         const float4* lds4){
    const v2f hc2 = vsplat(hc), hs2 = vsplat(hs), ns2 = vsplat(-hs);
    const int sl = ((lane ^ (lane>>1)) & 63) ^ (wv<<5);
    const int rb = (lane & 1) << 2;
    const float4* rdS = lds4 + (wv*16)*64 + sl;
    const float4* rdP = lds4 + ((wv^1)*16)*64 + (sl^32);
    #pragma unroll
    for (int u=0;u<8;++u){
        const int row = (u ^ (u>>1)) ^ rb;
        float4 Fr = rdS[row*64], Fi = rdS[(row+8)*64];
        float4 Gr = rdP[row*64], Gi = rdP[(row+8)*64];
        v2f ar,ai,br,bi, pr,pi,qr,qi;
        if ((u & 1) == 0){   // dest (k0..k3) <- src (x,y,w,z)
            ar.x=Fr.x; ar.y=Fr.y;  br.x=Fr.w; br.y=Fr.z;
            ai.x=Fi.x; ai.y=Fi.y;  bi.x=Fi.w; bi.y=Fi.z;
            pr.x=Gr.x; pr.y=Gr.y;  qr.x=Gr.w; qr.y=Gr.z;
            pi.x=Gi.x; pi.y=Gi.y;  qi.x=Gi.w; qi.y=Gi.z;
        } else {             // dest (k0..k3) <- src (z,w,y,x)
            ar.x=Fr.z; ar.y=Fr.w;  br.x=Fr.y; br.y=Fr.x;
            ai.x=Fi.z; ai.y=Fi.w;  bi.x=Fi.y; bi.y=Fi.x;
            pr.x=Gr.z; pr.y=Gr.w;  qr.x=Gr.y; qr.y=Gr.x;
            pi.x=Gi.z; pi.y=Gi.w;  qi.x=Gi.y; qi.y=Gi.x;
        }
        rx_upd<0>(re2[2*u],   im2[2*u],   ar, ai, pr, pi, hc2, hs2, ns2);
        rx_upd<0>(re2[2*u+1], im2[2*u+1], br, bi, qr, qi, hc2, hs2, ns2);
    }
}

// ---- init-time RX(w0): plain cross-wave exchange (no permute) ----
__device__ __forceinline__ void init_rx0(v2f (&re2)[16], v2f (&im2)[16],
                                         float hc, float hs, int lane, int wv, float4* lds4){
    const v2f hc2 = vsplat(hc), hs2 = vsplat(hs), ns2 = vsplat(-hs);
    exch_write(re2, im2, lane, wv, lds4);
    __syncthreads();
    const float4* rd = lds4 + ((wv^1)*16)*64 + lane;
    #pragma unroll
    for (int u=0;u<8;++u){
        float4 Fr = rd[u*64], Fi = rd[(u+8)*64];
        v2f prl,pil,prh,pih;
        prl.x=Fr.x; prl.y=Fr.y; prh.x=Fr.z; prh.y=Fr.w;
        pil.x=Fi.x; pil.y=Fi.y; pih.x=Fi.z; pih.y=Fi.w;
        rx_upd<0>(re2[2*u],   im2[2*u],   re2[2*u],   im2[2*u],   prl, pil, hc2, hs2, ns2);
        rx_upd<0>(re2[2*u+1], im2[2*u+1], re2[2*u+1], im2[2*u+1], prh, pih, hc2, hs2, ns2);
    }
    __syncthreads();
}

// ---- per-layer RX gates w1..w11 (canonical masks) ----
template<int W>
__device__ __forceinline__ void gates_w(v2f (&re2)[16], v2f (&im2)[16],
                                        const float2* __restrict__ tb, int lane){
    const float2 t = tb[W];
    rx_canon<W>(re2, im2, t.x, t.y, lane);
    if constexpr (W+1 < NQ) gates_w<W+1>(re2, im2, tb, lane);
}

// ---- init RX w1..w11 ----
template<int W>
__device__ __forceinline__ void init_w(v2f (&re2)[16], v2f (&im2)[16],
                                       const float* __restrict__ xb, int lane){
    float hs, hc;
    __sincosf(xb[W]*1.5707963267948966f, &hs, &hc);
    rx_canon<W>(re2, im2, hc, hs, lane);
    if constexpr (W+1 < NQ) init_w<W+1>(re2, im2, xb, lane);
}

// ---------------------------------------------------------------------------
// Workspace layout (floats): [0,192) tRX float2[8][12] (cos,sin of RX th/2)
//                            [192,256) tTH float[8][8] (RZ th/2, w=0..6)
//                            [256,768) tJ float4[8][16] (cos b_{2t}, cos b_{2t+1},
//                                                        sin b_{2t}, sin b_{2t+1})
// ---------------------------------------------------------------------------
__global__ void prep_kernel(const float* __restrict__ P, float* __restrict__ ws){
    const int i = threadIdx.x;   // 128 threads
    float2* tRX = (float2*)ws;
    float*  tTH = ws + 192;
    float4* tJ  = (float4*)(ws + 256);
    if (i < 96){
        const int l = i/12, w = i%12;
        float2 v; __sincosf(P[l*24 + 2*w]*0.5f, &v.y, &v.x);
        tRX[i] = v;
    }
    if (i < 64){
        const int l = i>>3, w = i&7;
        tTH[i] = (w < 7) ? P[l*24 + 2*w + 1]*0.5f : 0.f;
    }
    {
        const int l = i>>4, t = i&15;
        float br[2], bi[2];
        #pragma unroll
        for (int k=0;k<2;++k){
            const int j = 2*t + k;
            float beta = 0.f;
            #pragma unroll
            for (int w=7; w<12; ++w){
                const float th = P[l*24 + 2*w + 1]*0.5f;
                beta += ((j >> (11-w)) & 1) ? th : -th;
            }
            __sincosf(beta, &bi[k], &br[k]);
        }
        float4 v; v.x=br[0]; v.y=br[1]; v.z=bi[0]; v.w=bi[1];
        tJ[i] = v;
    }
}

__global__ __launch_bounds__(128, 2) void qnn_kernel(const float* __restrict__ x,
                                                     const float* __restrict__ ws,
                                                     const float* __restrict__ Wm,
                                                     float* __restrict__ out)
{
    __shared__ float4 lds4[2*16*64];   // 32 KB
    const int lane = threadIdx.x & 63;
    const int wv   = threadIdx.x >> 6;
    const int b    = blockIdx.x;

    const float2* tRX = (const float2*)ws;
    const float*  tTH = ws + 192;
    const float4* tJ  = (const float4*)(ws + 256);

    v2f re2[16], im2[16];
    #pragma unroll
    for (int t=0;t<16;++t){ re2[t] = vsplat(0.f); im2[t] = vsplat(0.f); }
    if (threadIdx.x == 0) re2[0].x = 1.0f;

    const float* xb = x + b*NQ;
    init_w<1>(re2, im2, xb, lane);
    {
        float hs0, hc0;
        __sincosf(xb[0]*1.5707963267948966f, &hs0, &hc0);
        init_rx0(re2, im2, hc0, hs0, lane, wv, lds4);
    }

    #pragma unroll 1
    for (int l = 0; l < NLAYERS; ++l){
        const float2* tb = tRX + l*12;
        const float2 t0 = tb[0];
        exch_write(re2, im2, lane, wv, lds4);
        __syncthreads();
        perm_rx0(re2, im2, t0.x, t0.y, lane, wv, lds4);      // CNOT restore + RX(w0)
        gates_w<1>(re2, im2, tb, lane);                      // RX w1..w11

        // ---- fused RZ (all 12 wires) ----
        const float* th = tTH + l*8;
        float alpha = wv ? th[0] : -th[0];
        #pragma unroll
        for (int w=1; w<=6; ++w)
            alpha += ((lane >> (6-w)) & 1) ? th[w] : -th[w];
        float sa, ca;
        __sincosf(alpha, &sa, &ca);
        const v2f vca = vsplat(ca), vsa = vsplat(sa), vna = vsplat(-sa);
        const float4* tj = tJ + l*16;
        #pragma unroll
        for (int t=0;t<16;++t){
            const float4 J = tj[t];
            v2f jr; jr.x=J.x; jr.y=J.y;
            v2f ji; ji.x=J.z; ji.y=J.w;
            const v2f cr = vfma(vca, jr, vna*ji);   // cos(a+b) pair
            const v2f ci = vfma(vca, ji, vsa*jr);   // sin(a+b) pair
            const v2f nci = -ci;
            const v2f r = re2[t], m = im2[t];
            re2[t] = vfma(r, cr, m*nci);
            im2[t] = vfma(m, cr, r*ci);
        }
        __syncthreads();
    }

    // ---- PauliZ expvals (state is CANONICAL after per-layer restore) ----
    v2f S = vsplat(0.f), S7 = vsplat(0.f), S8 = vsplat(0.f), S9 = vsplat(0.f), S10 = vsplat(0.f);
    #pragma unroll
    for (int t=0;t<16;++t){
        v2f p2 = __builtin_elementwise_fma(re2[t], re2[t], im2[t]*im2[t]);
        S += p2;
        S7  += (t&8)? -p2 : p2;   // wire 7  (j bit4)
        S8  += (t&4)? -p2 : p2;   // wire 8  (j bit3)
        S9  += (t&2)? -p2 : p2;   // wire 9  (j bit2)
        S10 += (t&1)? -p2 : p2;   // wire 10 (j bit1)
    }
    const float s0 = S.x + S.y;

    float z[12];
    z[0] = wv ? -s0 : s0;
    #pragma unroll
    for (int w=1; w<=6; ++w) z[w] = ((lane >> (6-w)) & 1) ? -s0 : s0;
    z[7]  = S7.x + S7.y;
    z[8]  = S8.x + S8.y;
    z[9]  = S9.x + S9.y;
    z[10] = S10.x + S10.y;
    z[11] = S.x - S.y;            // wire 11 (j bit0 = component)

    #pragma unroll
    for (int m=1; m<64; m<<=1){
        #pragma unroll
        for (int w=0; w<12; ++w) z[w] += __shfl_xor(z[w], m, 64);
    }

    float* sh = (float*)lds4;
    if (lane == 0){
        #pragma unroll
        for (int w=0; w<12; ++w) sh[wv*12 + w] = z[w];
    }
    __syncthreads();
    if (wv == 0){
        float t = 0.f;
        if (lane < 12){
            #pragma unroll
            for (int w=0; w<12; ++w){
                float zz = sh[w] + sh[12+w];
                t = fmaf(zz, Wm[w*12 + lane], t);
            }
            t = fmaxf(t, 0.f);
        }
        #pragma unroll
        for (int m=1; m<16; m<<=1) t += __shfl_xor(t, m, 64);
        if (lane == 0) out[b] = t;
    }
}

extern "C" void kernel_launch(void* const* d_in, const int* in_sizes, int n_in,
                              void* d_out, int out_size, void* d_ws, size_t ws_size,
                              hipStream_t stream) {
    const float* x  = (const float*)d_in[0];
    const float* P  = (const float*)d_in[1];
    const float* Wm = (const float*)d_in[2];
    float* out = (float*)d_out;
    float* ws  = (float*)d_ws;    // 768 floats = 3 KB
    prep_kernel<<<1, 128, 0, stream>>>(P, ws);
    qnn_kernel<<<BATCH, 128, 0, stream>>>(x, ws, Wm, out);
}